// Round 9
// baseline (411.135 us; speedup 1.0000x reference)
//
#include <hip/hip_runtime.h>
#include <math.h>

#define NOFF 44
#define NSP 11
#define HH 16
#define NN 4096
#define HD 64
#define QB 64          // queries per block (4 waves x 16)
#define BAND 96        // QB + 32 dense-band rows staged in LDS
#define LPAD 68        // padded row stride (floats)

__device__ __forceinline__ float dot4(float4 a, float4 b) {
    return a.x*b.x + a.y*b.y + a.z*b.z + a.w*b.w;
}

// Quarter-transposed: lane = (query q=lane&15, chunk-group cg=lane>>4).
// Each lane owns 16 floats (chunk cg) of query nq. Scores s[44] are
// per-lane (4x redundant over cg) -> cheap softmax, 2-shfl reduce.
__global__ __launch_bounds__(256, 3)
void dsq_attn_kernel(const float* __restrict__ q,
                     const float* __restrict__ k,
                     const float* __restrict__ v,
                     const float* __restrict__ pb,   // [44][16]
                     float* __restrict__ out)
{
    constexpr int SOFF[NSP] = {48,64,96,128,192,256,384,512,768,1024,1536};

    __shared__ float k_lds[BAND * LPAD];
    __shared__ float v_lds[BAND * LPAD];

    // XCD-aware bijective swizzle: 4096 blocks, 8 XCDs -> contiguous ranges.
    int b    = blockIdx.x;
    int bid0 = (b & 7) * 512 + (b >> 3);
    int bh    = bid0 >> 6;          // [0,64) = b*H + h
    int ntile = bid0 & 63;          // 64 queries each

    int tid  = (int)threadIdx.x;
    int lane = tid & 63;
    int wv   = tid >> 6;            // wave 0..3
    int q16  = lane & 15;           // query within wave
    int cg   = lane >> 4;           // chunk group 0..3 (16 floats each)
    int cb   = cg << 4;             // chunk base float index

    int n0 = ntile * QB;
    int nq = n0 + wv * 16 + q16;
    int h  = bh & (HH - 1);

    const size_t basebh = (size_t)bh * NN * HD;
    const float* kp = k + basebh;
    const float* vp = v + basebh;

    // ---- cooperative stage of band rows [n0-32, n0+64) ----
    // 1536 float4 per tensor; 256 threads x 6; coalesced 256B per row-group.
#pragma unroll
    for (int i = 0; i < 6; ++i) {
        int idx = tid + i * 256;
        int row = idx >> 4;
        int c   = (idx & 15) << 2;
        int gr  = n0 - 32 + row;
        gr = gr < 0 ? 0 : gr;       // clamped rows masked later
        *(float4*)(k_lds + row * LPAD + c) = *(const float4*)(kp + (size_t)gr * HD + c);
        *(float4*)(v_lds + row * LPAD + c) = *(const float4*)(vp + (size_t)gr * HD + c);
    }

    // ---- q fragment: 16 floats of query nq, chunk cg ----
    const float* qrow = q + basebh + (size_t)nq * HD + cb;
    float4 qv0 = *(const float4*)(qrow + 0);
    float4 qv1 = *(const float4*)(qrow + 4);
    float4 qv2 = *(const float4*)(qrow + 8);
    float4 qv3 = *(const float4*)(qrow + 12);

    const float sc = 0.125f;        // 1/sqrt(64)
    float s[NOFF];

    // ---- sparse QK from global (overlaps staging; independent of LDS) ----
#pragma unroll
    for (int j = 0; j < NSP; ++j) {
        int r  = nq - SOFF[j];
        int rc = r < 0 ? 0 : r;
        const float* kr = kp + (size_t)rc * HD + cb;
        float4 a0 = *(const float4*)(kr + 0);
        float4 a1 = *(const float4*)(kr + 4);
        float4 a2 = *(const float4*)(kr + 8);
        float4 a3 = *(const float4*)(kr + 12);
        float t = (dot4(qv0, a0) + dot4(qv1, a1)) + (dot4(qv2, a2) + dot4(qv3, a3));
        t += __shfl_xor(t, 16);
        t += __shfl_xor(t, 32);
        s[33 + j] = (r >= 0) ? fmaf(t, sc, pb[(33 + j) * HH + h]) : -INFINITY;
    }

    __syncthreads();

    // ---- dense QK from LDS (offsets 0..32) ----
    int rbw = wv * 16 + q16 + 32;   // band-local row for offset d: rbw - d
#pragma unroll
    for (int d = 0; d <= 32; ++d) {
        const float* kr = k_lds + (rbw - d) * LPAD + cb;
        float4 a0 = *(const float4*)(kr + 0);
        float4 a1 = *(const float4*)(kr + 4);
        float4 a2 = *(const float4*)(kr + 8);
        float4 a3 = *(const float4*)(kr + 12);
        float t = (dot4(qv0, a0) + dot4(qv1, a1)) + (dot4(qv2, a2) + dot4(qv3, a3));
        t += __shfl_xor(t, 16);
        t += __shfl_xor(t, 32);
        s[d] = (nq >= d) ? fmaf(t, sc, pb[d * HH + h]) : -INFINITY;
    }

    // ---- softmax over 44 (per-lane, 4x redundant; d=0 always valid) ----
    float m = s[0];
#pragma unroll
    for (int i = 1; i < NOFF; ++i) m = fmaxf(m, s[i]);
    float l = 0.0f;
#pragma unroll
    for (int i = 0; i < NOFF; ++i) {
        float e = __expf(s[i] - m);   // exp(-inf)=0 for invalid offsets
        s[i] = e;
        l += e;
    }

    // ---- PV: lane accumulates its 16-float out chunk ----
    float4 ac0 = make_float4(0.f,0.f,0.f,0.f);
    float4 ac1 = make_float4(0.f,0.f,0.f,0.f);
    float4 ac2 = make_float4(0.f,0.f,0.f,0.f);
    float4 ac3 = make_float4(0.f,0.f,0.f,0.f);

    // sparse PV from global
#pragma unroll
    for (int j = 0; j < NSP; ++j) {
        int r  = nq - SOFF[j];
        int rc = r < 0 ? 0 : r;
        const float* vr = vp + (size_t)rc * HD + cb;
        float4 b0 = *(const float4*)(vr + 0);
        float4 b1 = *(const float4*)(vr + 4);
        float4 b2 = *(const float4*)(vr + 8);
        float4 b3 = *(const float4*)(vr + 12);
        float e = s[33 + j];          // 0 for invalid
        ac0.x = fmaf(e, b0.x, ac0.x); ac0.y = fmaf(e, b0.y, ac0.y);
        ac0.z = fmaf(e, b0.z, ac0.z); ac0.w = fmaf(e, b0.w, ac0.w);
        ac1.x = fmaf(e, b1.x, ac1.x); ac1.y = fmaf(e, b1.y, ac1.y);
        ac1.z = fmaf(e, b1.z, ac1.z); ac1.w = fmaf(e, b1.w, ac1.w);
        ac2.x = fmaf(e, b2.x, ac2.x); ac2.y = fmaf(e, b2.y, ac2.y);
        ac2.z = fmaf(e, b2.z, ac2.z); ac2.w = fmaf(e, b2.w, ac2.w);
        ac3.x = fmaf(e, b3.x, ac3.x); ac3.y = fmaf(e, b3.y, ac3.y);
        ac3.z = fmaf(e, b3.z, ac3.z); ac3.w = fmaf(e, b3.w, ac3.w);
    }

    // dense PV from LDS
#pragma unroll
    for (int d = 0; d <= 32; ++d) {
        const float* vr = v_lds + (rbw - d) * LPAD + cb;
        float4 b0 = *(const float4*)(vr + 0);
        float4 b1 = *(const float4*)(vr + 4);
        float4 b2 = *(const float4*)(vr + 8);
        float4 b3 = *(const float4*)(vr + 12);
        float e = s[d];
        ac0.x = fmaf(e, b0.x, ac0.x); ac0.y = fmaf(e, b0.y, ac0.y);
        ac0.z = fmaf(e, b0.z, ac0.z); ac0.w = fmaf(e, b0.w, ac0.w);
        ac1.x = fmaf(e, b1.x, ac1.x); ac1.y = fmaf(e, b1.y, ac1.y);
        ac1.z = fmaf(e, b1.z, ac1.z); ac1.w = fmaf(e, b1.w, ac1.w);
        ac2.x = fmaf(e, b2.x, ac2.x); ac2.y = fmaf(e, b2.y, ac2.y);
        ac2.z = fmaf(e, b2.z, ac2.z); ac2.w = fmaf(e, b2.w, ac2.w);
        ac3.x = fmaf(e, b3.x, ac3.x); ac3.y = fmaf(e, b3.y, ac3.y);
        ac3.z = fmaf(e, b3.z, ac3.z); ac3.w = fmaf(e, b3.w, ac3.w);
    }

    float inv = 1.0f / l;
    float* op = out + basebh + (size_t)nq * HD + cb;
    *(float4*)(op + 0)  = make_float4(ac0.x*inv, ac0.y*inv, ac0.z*inv, ac0.w*inv);
    *(float4*)(op + 4)  = make_float4(ac1.x*inv, ac1.y*inv, ac1.z*inv, ac1.w*inv);
    *(float4*)(op + 8)  = make_float4(ac2.x*inv, ac2.y*inv, ac2.z*inv, ac2.w*inv);
    *(float4*)(op + 12) = make_float4(ac3.x*inv, ac3.y*inv, ac3.z*inv, ac3.w*inv);
}

extern "C" void kernel_launch(void* const* d_in, const int* in_sizes, int n_in,
                              void* d_out, int out_size, void* d_ws, size_t ws_size,
                              hipStream_t stream) {
    const float* q  = (const float*)d_in[0];
    const float* k  = (const float*)d_in[1];
    const float* v  = (const float*)d_in[2];
    const float* pb = (const float*)d_in[3];
    float* out = (float*)d_out;

    // B*H*N / QB = 262144 / 64 = 4096 blocks
    dim3 grid(4096), block(256);
    hipLaunchKernelGGL(dsq_attn_kernel, grid, block, 0, stream, q, k, v, pb, out);
}